// Round 13
// baseline (131.387 us; speedup 1.0000x reference)
//
#include <hip/hip_runtime.h>
#include <hip/hip_bf16.h>
#include <math.h>

// Problem constants (match reference)
#define B_ 16
#define L_ 256
#define A_ 128
#define D_ 4
#define H_ 64
#define DFF_ 256
#define PRED_ 64
#define COUT_ 8

// ws layout (floats)
// gate weights SoA, exp2-prescaled: [g][d][64], g=0:z (x L2E), g=1:h (x 2*L2E)
#define WS_GW   0
// gate biases, same prescale: [g][64]
#define WS_GB   512
#define WS_PART 640                       // [B*L][64] per-(b,l) agent-sums

#define L2E 1.4426950408889634f

typedef float v2 __attribute__((ext_vector_type(2)));

// ---------------------------------------------------------------------------
// Kernel 0: fold gate weights. Wg' = (W_g @ Lg_w[0:64,:]) * s_g, stored SoA
// [d][j]; bg' = (b_g @ Lg_w + Lg_b) * s_g.  s_z = log2(e), s_h = 2*log2(e)
// (folding the exp2 argument scale).  R gate is dead code: dropped.
// ---------------------------------------------------------------------------
__global__ __launch_bounds__(256) void precomp_kernel(
    const float* __restrict__ W_z, const float* __restrict__ b_z,
    const float* __restrict__ W_h, const float* __restrict__ b_h,
    const float* __restrict__ Lz_w, const float* __restrict__ Lz_b,
    const float* __restrict__ Lh_w, const float* __restrict__ Lh_b,
    float* __restrict__ ws)
{
    int t = threadIdx.x;
    for (int idx = t; idx < 512; idx += 256) {
        int g = idx >> 8;          // 0 = z, 1 = h
        int d = (idx >> 6) & 3;
        int j = idx & 63;
        const float* W  = g ? W_h  : W_z;
        const float* Lw = g ? Lh_w : Lz_w;
        float acc = 0.f;
        for (int h = 0; h < 64; ++h)
            acc += W[d * 64 + h] * Lw[h * 64 + j];
        ws[WS_GW + g * 256 + d * 64 + j] = acc * (g ? 2.f * L2E : L2E);
    }
    if (t < 128) {
        int g = t >> 6;
        int j = t & 63;
        const float* bg = g ? b_h  : b_z;
        const float* Lw = g ? Lh_w : Lz_w;
        const float* Lb = g ? Lh_b : Lz_b;
        float acc = Lb[j];
        for (int h = 0; h < 64; ++h)
            acc += bg[h] * Lw[h * 64 + j];
        ws[WS_GB + g * 64 + j] = acc * (g ? 2.f * L2E : L2E);
    }
}

// ---------------------------------------------------------------------------
// Kernel 1: 512-thread block = TWO (b,l) tiles (waves 0-3 / 4-7), each tile
// processed by 256 threads exactly as round 12: thread serves rows r, r+64
// and column-quarter q; one xe/xs LDS read feeds both rows (halved DS count);
// 64 pairwise weights cached in registers (fully-unrolled const indexing).
// Rationale: 512-thread blocks measure 50-70% occupancy vs 27% for
// 256-thread blocks — restores DS/VALU overlap lost in round 12.
// (512,6): proven no-spill reg-cap config; live set ~76 < cap 84.
// ---------------------------------------------------------------------------
__global__ __launch_bounds__(512, 6) void tgcn_kernel(
    const float* __restrict__ x,
    const float* __restrict__ ws_w,
    float* __restrict__ part)
{
    __shared__ float4 xr4_s[2][128];  // per-tile agent features
    __shared__ float4 xs4_s[2][128];  // per-tile dinv[e]*xr[e]
    __shared__ float4 M4_s[2][128];   // per-tile m rows (pre-scaled)
    __shared__ float  gw_s[512];      // shared prescaled gate weights
    __shared__ float  gb_s[128];      // shared prescaled gate biases
    __shared__ float  red_s[2][4][64];

    const int th   = threadIdx.x;
    const int half = th >> 8;         // which tile in this block
    const int t    = th & 255;        // within-tile thread id
    const int bl   = (blockIdx.x << 1) | half;

    // ---- stage ----
    if (t < 128)
        xr4_s[half][t] = ((const float4*)(x + (size_t)bl * (A_ * D_)))[t];
    gw_s[th] = ws_w[WS_GW + th];      // 512 threads cover 512 entries
    if (th < 128) gb_s[th] = ws_w[WS_GB + th];
    __syncthreads();

    const int r = t >> 2;             // row pair: rows r, r+64  (r in 0..63)
    const int q = t & 3;              // column-quarter (interleaved)

    const float4 xa0 = xr4_s[half][r];
    const float4 xa1 = xr4_s[half][r + 64];
    const v2 a0_01 = {xa0.x, xa0.y};
    const v2 a0_23 = {xa0.z, xa0.w};
    const v2 a1_01 = {xa1.x, xa1.y};
    const v2 a1_23 = {xa1.z, xa1.w};

    // ---- pass 1: pairwise weights for both rows -> reg arrays + rowsums ----
    float wu[32];                     // weights for row r
    float wv[32];                     // weights for row r+64
    float rsA0 = 0.f, rsA1 = 0.f, rsB0 = 0.f, rsB1 = 0.f;
    #pragma unroll
    for (int k = 0; k < 32; ++k) {
        float4 xe = xr4_s[half][(k << 2) | q];   // one read, two rows
        v2 e01 = {xe.x, xe.y};
        v2 e23 = {xe.z, xe.w};
        v2 dA01 = a0_01 - e01;
        v2 dA23 = a0_23 - e23;
        v2 sA = dA01 * dA01;
        sA = __builtin_elementwise_fma(dA23, dA23, sA);
        float wA = fminf(__builtin_amdgcn_rsqf(sA.x + sA.y), 1.0e6f);
        v2 dB01 = a1_01 - e01;
        v2 dB23 = a1_23 - e23;
        v2 sB = dB01 * dB01;
        sB = __builtin_elementwise_fma(dB23, dB23, sB);
        float wB = fminf(__builtin_amdgcn_rsqf(sB.x + sB.y), 1.0e6f);
        wu[k] = wA;
        wv[k] = wB;
        if (k & 1) { rsA1 += wA; rsB1 += wB; }
        else       { rsA0 += wA; rsB0 += wB; }
    }
    float rsA = rsA0 + rsA1;
    float rsB = rsB0 + rsB1;
    rsA += __shfl_xor(rsA, 1); rsA += __shfl_xor(rsA, 2);
    rsB += __shfl_xor(rsB, 1); rsB += __shfl_xor(rsB, 2);
    const float dinvA = __builtin_amdgcn_rsqf(rsA);
    const float dinvB = __builtin_amdgcn_rsqf(rsB);
    if (q == 0) {
        xs4_s[half][r]      = make_float4(dinvA * xa0.x, dinvA * xa0.y,
                                          dinvA * xa0.z, dinvA * xa0.w);
        xs4_s[half][r + 64] = make_float4(dinvB * xa1.x, dinvB * xa1.y,
                                          dinvB * xa1.z, dinvB * xa1.w);
    }
    __syncthreads();

    // ---- pass 2: m(row) = w_row . xs, one read feeds both rows ----
    v2 mA01 = {0.f, 0.f};
    v2 mA23 = {0.f, 0.f};
    v2 mB01 = {0.f, 0.f};
    v2 mB23 = {0.f, 0.f};
    #pragma unroll
    for (int k = 0; k < 32; ++k) {
        float4 xu = xs4_s[half][(k << 2) | q];
        v2 u01 = {xu.x, xu.y};
        v2 u23 = {xu.z, xu.w};
        v2 wA2 = {wu[k], wu[k]};
        v2 wB2 = {wv[k], wv[k]};
        mA01 = __builtin_elementwise_fma(wA2, u01, mA01);
        mA23 = __builtin_elementwise_fma(wA2, u23, mA23);
        mB01 = __builtin_elementwise_fma(wB2, u01, mB01);
        mB23 = __builtin_elementwise_fma(wB2, u23, mB23);
    }
    float mA0 = mA01.x, mA1 = mA01.y, mA2 = mA23.x, mA3 = mA23.y;
    float mB0 = mB01.x, mB1 = mB01.y, mB2 = mB23.x, mB3 = mB23.y;
    mA0 += __shfl_xor(mA0, 1); mA0 += __shfl_xor(mA0, 2);
    mA1 += __shfl_xor(mA1, 1); mA1 += __shfl_xor(mA1, 2);
    mA2 += __shfl_xor(mA2, 1); mA2 += __shfl_xor(mA2, 2);
    mA3 += __shfl_xor(mA3, 1); mA3 += __shfl_xor(mA3, 2);
    mB0 += __shfl_xor(mB0, 1); mB0 += __shfl_xor(mB0, 2);
    mB1 += __shfl_xor(mB1, 1); mB1 += __shfl_xor(mB1, 2);
    mB2 += __shfl_xor(mB2, 1); mB2 += __shfl_xor(mB2, 2);
    mB3 += __shfl_xor(mB3, 1); mB3 += __shfl_xor(mB3, 2);
    if (q == 0) {
        M4_s[half][r]      = make_float4(dinvA * mA0, dinvA * mA1,
                                         dinvA * mA2, dinvA * mA3);
        M4_s[half][r + 64] = make_float4(dinvB * mB0, dinvB * mB1,
                                         dinvB * mB2, dinvB * mB3);
    }
    __syncthreads();

    // ---- gates, transposed: thread <-> column j, 32 agents per thread ----
    {
        const int j  = t & 63;
        const int g  = (t >> 6) & 3;           // wave-in-tile -> agent group
        const v2 W0 = {gw_s[j],       gw_s[256 + j]};
        const v2 W1 = {gw_s[64 + j],  gw_s[320 + j]};
        const v2 W2 = {gw_s[128 + j], gw_s[384 + j]};
        const v2 W3 = {gw_s[192 + j], gw_s[448 + j]};
        const v2 Bzh = {gb_s[j], gb_s[64 + j]};
        float acc = 0.f;
        #pragma unroll
        for (int i = 0; i < 32; ++i) {
            float4 mv = M4_s[half][g * 32 + i]; // wave-uniform broadcast
            v2 zh = __builtin_elementwise_fma((v2){mv.x, mv.x}, W0, Bzh);
            zh = __builtin_elementwise_fma((v2){mv.y, mv.y}, W1, zh);
            zh = __builtin_elementwise_fma((v2){mv.z, mv.z}, W2, zh);
            zh = __builtin_elementwise_fma((v2){mv.w, mv.w}, W3, zh);
            float ez = __builtin_amdgcn_exp2f(zh.x);
            float e2 = __builtin_amdgcn_exp2f(zh.y);
            // (1-sigmoid)*tanh = (e2-1) / ((1+ez)*(1+e2)), one rcp
            float num = e2 - 1.f;
            float den = (1.f + ez) * (1.f + e2);
            float hv  = num * __builtin_amdgcn_rcpf(den);
            acc += fmaxf(hv, 0.f);
        }
        red_s[half][g][j] = acc;
    }
    __syncthreads();

    if (t < 64) {
        part[(size_t)bl * 64 + t] = red_s[half][0][t] + red_s[half][1][t]
                                  + red_s[half][2][t] + red_s[half][3][t];
    }
}

// ---------------------------------------------------------------------------
// Kernel 2: fused pool + decoder. One block of 1024 threads per batch.
// ---------------------------------------------------------------------------
__global__ __launch_bounds__(1024) void pooldec_kernel(
    const float* __restrict__ part,
    const float* __restrict__ D1_w, const float* __restrict__ D1_b,
    const float* __restrict__ D2_w, const float* __restrict__ D2_b,
    float* __restrict__ out)
{
    __shared__ float red_s[16][64];
    __shared__ float pooled_s[64];
    __shared__ float t1_s[256];
    const int t = threadIdx.x, b = blockIdx.x;

    // ---- pool over L: 16 groups x 16 rows ----
    {
        const int j = t & 63, g = t >> 6;
        const float* pb = part + ((size_t)b * L_ + g * 16) * 64;
        float s = 0.f;
        #pragma unroll
        for (int i = 0; i < 16; ++i) s += pb[i * 64 + j];
        red_s[g][j] = s;
    }
    __syncthreads();
    if (t < 64) {
        float s = 0.f;
        #pragma unroll
        for (int g = 0; g < 16; ++g) s += red_s[g][t];
        pooled_s[t] = s * (1.f / ((float)L_ * (float)A_));
    }
    __syncthreads();

    // ---- D1: 256 outputs, 4 threads per output (16 h each) ----
    {
        const int o = t >> 2, sub = t & 3;
        float acc = 0.f;
        #pragma unroll
        for (int hh = 0; hh < 16; ++hh) {
            int h = sub * 16 + hh;
            acc += pooled_s[h] * D1_w[h * 256 + o];
        }
        acc += __shfl_xor(acc, 1);
        acc += __shfl_xor(acc, 2);
        if (sub == 0) t1_s[o] = fmaxf(acc + D1_b[o], 0.f);
    }
    __syncthreads();

    // ---- D2: 512 outputs, 2 threads per output (128 k each) ----
    {
        const int o = t >> 1, kh = t & 1;
        float acc = 0.f;
        for (int kk = 0; kk < 128; ++kk) {
            int k = kh * 128 + kk;
            acc += t1_s[k] * D2_w[k * 512 + o];
        }
        acc += __shfl_xor(acc, 1);
        if (kh == 0) out[(size_t)b * 512 + o] = acc + D2_b[o];
    }
}

// ---------------------------------------------------------------------------
extern "C" void kernel_launch(void* const* d_in, const int* in_sizes, int n_in,
                              void* d_out, int out_size, void* d_ws, size_t ws_size,
                              hipStream_t stream)
{
    const float* x    = (const float*)d_in[0];
    // d_in[1..3]: x_mark_enc, x_dec, x_mark_dec — unused by the reference
    const float* W_z  = (const float*)d_in[4];
    const float* b_z  = (const float*)d_in[5];
    // d_in[6], d_in[7]: W_r, b_r — dead code in the reference
    const float* W_h  = (const float*)d_in[8];
    const float* b_h  = (const float*)d_in[9];
    const float* Lz_w = (const float*)d_in[10];
    const float* Lz_b = (const float*)d_in[11];
    // d_in[12], d_in[13]: Lr_w, Lr_b — dead
    const float* Lh_w = (const float*)d_in[14];
    const float* Lh_b = (const float*)d_in[15];
    const float* D1_w = (const float*)d_in[16];
    const float* D1_b = (const float*)d_in[17];
    const float* D2_w = (const float*)d_in[18];
    const float* D2_b = (const float*)d_in[19];

    float* ws  = (float*)d_ws;
    float* out = (float*)d_out;

    precomp_kernel<<<1, 256, 0, stream>>>(W_z, b_z, W_h, b_h,
                                          Lz_w, Lz_b, Lh_w, Lh_b, ws);
    tgcn_kernel<<<B_ * L_ / 2, 512, 0, stream>>>(x, ws, ws + WS_PART);
    pooldec_kernel<<<B_, 1024, 0, stream>>>(ws + WS_PART, D1_w, D1_b,
                                            D2_w, D2_b, out);
}

// Round 14
// 88.809 us; speedup vs baseline: 1.4794x; 1.4794x over previous
//
#include <hip/hip_runtime.h>
#include <hip/hip_bf16.h>
#include <math.h>

// Problem constants (match reference)
#define B_ 16
#define L_ 256
#define A_ 128
#define D_ 4
#define H_ 64
#define DFF_ 256
#define PRED_ 64
#define COUT_ 8

// ws layout (floats)
// gate weights SoA, exp2-prescaled: [g][d][64], g=0:z (x L2E), g=1:h (x 2*L2E)
#define WS_GW   0
// gate biases, same prescale: [g][64]
#define WS_GB   512
#define WS_PART 640                       // [B*L][64] per-(b,l) agent-sums

#define L2E 1.4426950408889634f

typedef float v2 __attribute__((ext_vector_type(2)));

// ---------------------------------------------------------------------------
// Kernel 0: fold gate weights, PARALLEL: 5 blocks x 128 threads, one output
// per thread (512 weight entries + 128 bias entries = 640).
// Wg' = (W_g @ Lg_w[0:64,:]) * s_g stored SoA [d][j]; bg' likewise.
// s_z = log2(e), s_h = 2*log2(e). R gate is dead code: dropped.
// ---------------------------------------------------------------------------
__global__ __launch_bounds__(128) void precomp_kernel(
    const float* __restrict__ W_z, const float* __restrict__ b_z,
    const float* __restrict__ W_h, const float* __restrict__ b_h,
    const float* __restrict__ Lz_w, const float* __restrict__ Lz_b,
    const float* __restrict__ Lh_w, const float* __restrict__ Lh_b,
    float* __restrict__ ws)
{
    const int idx = blockIdx.x * 128 + threadIdx.x;   // 0..639
    if (idx < 512) {
        // weight entry: g (0=z,1=h), d, j
        const int g = idx >> 8;
        const int d = (idx >> 6) & 3;
        const int j = idx & 63;
        const float* W  = g ? W_h  : W_z;
        const float* Lw = g ? Lh_w : Lz_w;
        float acc = 0.f;
        #pragma unroll 8
        for (int h = 0; h < 64; ++h)
            acc += W[d * 64 + h] * Lw[h * 64 + j];
        ws[WS_GW + g * 256 + d * 64 + j] = acc * (g ? 2.f * L2E : L2E);
    } else {
        // bias entry
        const int i = idx - 512;           // 0..127
        const int g = i >> 6;
        const int j = i & 63;
        const float* bg = g ? b_h  : b_z;
        const float* Lw = g ? Lh_w : Lz_w;
        const float* Lb = g ? Lh_b : Lz_b;
        float acc = Lb[j];
        #pragma unroll 8
        for (int h = 0; h < 64; ++h)
            acc += bg[h] * Lw[h * 64 + j];
        ws[WS_GB + g * 64 + j] = acc * (g ? 2.f * L2E : L2E);
    }
}

// ---------------------------------------------------------------------------
// Kernel 1: one block of 512 threads per (b,l). Each thread serves TWO agent
// rows (r, r+64) and one column-EIGHTH q (cols e = 8k|q, k=0..15): each
// xe LDS read feeds two rows -> pass DS instrs halved vs round 9.
// Pass 2 RECOMPUTES the pairwise weight (no register cache -> live ~55 regs,
// no spill under the empirical cap law cap~256/arg2; (512,4) -> cap 64) and
// reads dinv_s[e] (b32, 8 distinct banks, broadcast within bank: free-ish).
// All LDS reads conflict-free: 8 distinct float4 addrs span all 32 banks.
//   w(r,e)  = min(rsq(|xr[r]-xr[e]|^2), 1e6)  (diag exact: rsq(0)=inf)
//   dinv[r] = rsq(sum_e w(r,e))
//   m[r]    = dinv[r] * sum_e w(r,e)*dinv[e]*xr[e]
//   h[r][j] = relu((1-sigmoid(zp))*tanh(hp)); part[bl][j] = sum_r h[r][j]
// ---------------------------------------------------------------------------
__global__ __launch_bounds__(512, 4) void tgcn_kernel(
    const float* __restrict__ x,
    const float* __restrict__ ws_w,
    float* __restrict__ part)
{
    __shared__ float4 xr4_s[128];     // agent features
    __shared__ float  dinv_s[128];    // per-agent 1/sqrt(rowsum)
    __shared__ float4 M4_s[128];      // per-row m (pre-scaled by dinv[r])
    __shared__ float  gw_s[512];      // [g][d][64] prescaled gate weights
    __shared__ float  gb_s[128];      // [g][64] prescaled gate biases
    __shared__ float  red_s[8][64];

    const int t  = threadIdx.x;
    const int bl = blockIdx.x;

    // ---- stage ----
    if (t < 128)
        xr4_s[t] = ((const float4*)(x + (size_t)bl * (A_ * D_)))[t];
    gw_s[t] = ws_w[WS_GW + t];
    if (t < 128) gb_s[t] = ws_w[WS_GB + t];
    __syncthreads();

    const int r = t >> 3;             // row pair: rows r, r+64  (r in 0..63)
    const int q = t & 7;              // column-eighth (interleaved)

    const float4 xa0 = xr4_s[r];
    const float4 xa1 = xr4_s[r + 64];

    // ---- pass 1: rowsums for both rows (w recomputed later, not cached) ----
    float rsA = 0.f, rsB = 0.f;
    #pragma unroll
    for (int k = 0; k < 16; ++k) {
        float4 xe = xr4_s[(k << 3) | q];       // one read, two rows
        float ax = xa0.x - xe.x, ay = xa0.y - xe.y;
        float az = xa0.z - xe.z, aw = xa0.w - xe.w;
        float dA = ax * ax + ay * ay + az * az + aw * aw;
        rsA += fminf(__builtin_amdgcn_rsqf(dA), 1.0e6f);
        float bx = xa1.x - xe.x, by = xa1.y - xe.y;
        float bz = xa1.z - xe.z, bw = xa1.w - xe.w;
        float dB = bx * bx + by * by + bz * bz + bw * bw;
        rsB += fminf(__builtin_amdgcn_rsqf(dB), 1.0e6f);
    }
    rsA += __shfl_xor(rsA, 1); rsA += __shfl_xor(rsA, 2); rsA += __shfl_xor(rsA, 4);
    rsB += __shfl_xor(rsB, 1); rsB += __shfl_xor(rsB, 2); rsB += __shfl_xor(rsB, 4);
    const float dinvA = __builtin_amdgcn_rsqf(rsA);
    const float dinvB = __builtin_amdgcn_rsqf(rsB);
    if (q == 0) {
        dinv_s[r]      = dinvA;
        dinv_s[r + 64] = dinvB;
    }
    __syncthreads();

    // ---- pass 2: m(row) = sum_e w(row,e)*dinv_e*xr_e, w recomputed ----
    float mA0 = 0.f, mA1 = 0.f, mA2 = 0.f, mA3 = 0.f;
    float mB0 = 0.f, mB1 = 0.f, mB2 = 0.f, mB3 = 0.f;
    #pragma unroll
    for (int k = 0; k < 16; ++k) {
        const int e = (k << 3) | q;
        float4 xe = xr4_s[e];                  // b128, conflict-free
        float de = dinv_s[e];                  // b32, bank-broadcast
        float ax = xa0.x - xe.x, ay = xa0.y - xe.y;
        float az = xa0.z - xe.z, aw = xa0.w - xe.w;
        float dA = ax * ax + ay * ay + az * az + aw * aw;
        float wA = fminf(__builtin_amdgcn_rsqf(dA), 1.0e6f) * de;
        float bx = xa1.x - xe.x, by = xa1.y - xe.y;
        float bz = xa1.z - xe.z, bw = xa1.w - xe.w;
        float dB = bx * bx + by * by + bz * bz + bw * bw;
        float wB = fminf(__builtin_amdgcn_rsqf(dB), 1.0e6f) * de;
        mA0 = fmaf(wA, xe.x, mA0); mA1 = fmaf(wA, xe.y, mA1);
        mA2 = fmaf(wA, xe.z, mA2); mA3 = fmaf(wA, xe.w, mA3);
        mB0 = fmaf(wB, xe.x, mB0); mB1 = fmaf(wB, xe.y, mB1);
        mB2 = fmaf(wB, xe.z, mB2); mB3 = fmaf(wB, xe.w, mB3);
    }
    mA0 += __shfl_xor(mA0, 1); mA0 += __shfl_xor(mA0, 2); mA0 += __shfl_xor(mA0, 4);
    mA1 += __shfl_xor(mA1, 1); mA1 += __shfl_xor(mA1, 2); mA1 += __shfl_xor(mA1, 4);
    mA2 += __shfl_xor(mA2, 1); mA2 += __shfl_xor(mA2, 2); mA2 += __shfl_xor(mA2, 4);
    mA3 += __shfl_xor(mA3, 1); mA3 += __shfl_xor(mA3, 2); mA3 += __shfl_xor(mA3, 4);
    mB0 += __shfl_xor(mB0, 1); mB0 += __shfl_xor(mB0, 2); mB0 += __shfl_xor(mB0, 4);
    mB1 += __shfl_xor(mB1, 1); mB1 += __shfl_xor(mB1, 2); mB1 += __shfl_xor(mB1, 4);
    mB2 += __shfl_xor(mB2, 1); mB2 += __shfl_xor(mB2, 2); mB2 += __shfl_xor(mB2, 4);
    mB3 += __shfl_xor(mB3, 1); mB3 += __shfl_xor(mB3, 2); mB3 += __shfl_xor(mB3, 4);
    if (q == 0) {
        M4_s[r]      = make_float4(dinvA * mA0, dinvA * mA1,
                                   dinvA * mA2, dinvA * mA3);
        M4_s[r + 64] = make_float4(dinvB * mB0, dinvB * mB1,
                                   dinvB * mB2, dinvB * mB3);
    }
    __syncthreads();

    // ---- gates, transposed: thread <-> column j, 16 agents per wave ----
    {
        const int j = t & 63;
        const int g = t >> 6;                  // wave id 0..7 -> agent group
        const v2 W0 = {gw_s[j],       gw_s[256 + j]};
        const v2 W1 = {gw_s[64 + j],  gw_s[320 + j]};
        const v2 W2 = {gw_s[128 + j], gw_s[384 + j]};
        const v2 W3 = {gw_s[192 + j], gw_s[448 + j]};
        const v2 Bzh = {gb_s[j], gb_s[64 + j]};
        float acc = 0.f;
        #pragma unroll
        for (int i = 0; i < 16; ++i) {
            float4 mv = M4_s[g * 16 + i];      // wave-uniform broadcast
            v2 zh = __builtin_elementwise_fma((v2){mv.x, mv.x}, W0, Bzh);
            zh = __builtin_elementwise_fma((v2){mv.y, mv.y}, W1, zh);
            zh = __builtin_elementwise_fma((v2){mv.z, mv.z}, W2, zh);
            zh = __builtin_elementwise_fma((v2){mv.w, mv.w}, W3, zh);
            float ez = __builtin_amdgcn_exp2f(zh.x);
            float e2 = __builtin_amdgcn_exp2f(zh.y);
            // (1-sigmoid)*tanh = (e2-1) / ((1+ez)*(1+e2)), one rcp
            float num = e2 - 1.f;
            float den = (1.f + ez) * (1.f + e2);
            float hv  = num * __builtin_amdgcn_rcpf(den);
            acc += fmaxf(hv, 0.f);
        }
        red_s[g][j] = acc;
    }
    __syncthreads();

    if (t < 64) {
        float s = red_s[0][t] + red_s[1][t] + red_s[2][t] + red_s[3][t]
                + red_s[4][t] + red_s[5][t] + red_s[6][t] + red_s[7][t];
        part[(size_t)bl * 64 + t] = s;
    }
}

// ---------------------------------------------------------------------------
// Kernel 2: fused pool + decoder. One block of 1024 threads per batch.
// ---------------------------------------------------------------------------
__global__ __launch_bounds__(1024) void pooldec_kernel(
    const float* __restrict__ part,
    const float* __restrict__ D1_w, const float* __restrict__ D1_b,
    const float* __restrict__ D2_w, const float* __restrict__ D2_b,
    float* __restrict__ out)
{
    __shared__ float red_s[16][64];
    __shared__ float pooled_s[64];
    __shared__ float t1_s[256];
    const int t = threadIdx.x, b = blockIdx.x;

    // ---- pool over L: 16 groups x 16 rows ----
    {
        const int j = t & 63, g = t >> 6;
        const float* pb = part + ((size_t)b * L_ + g * 16) * 64;
        float s = 0.f;
        #pragma unroll
        for (int i = 0; i < 16; ++i) s += pb[i * 64 + j];
        red_s[g][j] = s;
    }
    __syncthreads();
    if (t < 64) {
        float s = 0.f;
        #pragma unroll
        for (int g = 0; g < 16; ++g) s += red_s[g][t];
        pooled_s[t] = s * (1.f / ((float)L_ * (float)A_));
    }
    __syncthreads();

    // ---- D1: 256 outputs, 4 threads per output (16 h each) ----
    {
        const int o = t >> 2, sub = t & 3;
        float acc = 0.f;
        #pragma unroll
        for (int hh = 0; hh < 16; ++hh) {
            int h = sub * 16 + hh;
            acc += pooled_s[h] * D1_w[h * 256 + o];
        }
        acc += __shfl_xor(acc, 1);
        acc += __shfl_xor(acc, 2);
        if (sub == 0) t1_s[o] = fmaxf(acc + D1_b[o], 0.f);
    }
    __syncthreads();

    // ---- D2: 512 outputs, 2 threads per output (128 k each) ----
    {
        const int o = t >> 1, kh = t & 1;
        float acc = 0.f;
        for (int kk = 0; kk < 128; ++kk) {
            int k = kh * 128 + kk;
            acc += t1_s[k] * D2_w[k * 512 + o];
        }
        acc += __shfl_xor(acc, 1);
        if (kh == 0) out[(size_t)b * 512 + o] = acc + D2_b[o];
    }
}

// ---------------------------------------------------------------------------
extern "C" void kernel_launch(void* const* d_in, const int* in_sizes, int n_in,
                              void* d_out, int out_size, void* d_ws, size_t ws_size,
                              hipStream_t stream)
{
    const float* x    = (const float*)d_in[0];
    // d_in[1..3]: x_mark_enc, x_dec, x_mark_dec — unused by the reference
    const float* W_z  = (const float*)d_in[4];
    const float* b_z  = (const float*)d_in[5];
    // d_in[6], d_in[7]: W_r, b_r — dead code in the reference
    const float* W_h  = (const float*)d_in[8];
    const float* b_h  = (const float*)d_in[9];
    const float* Lz_w = (const float*)d_in[10];
    const float* Lz_b = (const float*)d_in[11];
    // d_in[12], d_in[13]: Lr_w, Lr_b — dead
    const float* Lh_w = (const float*)d_in[14];
    const float* Lh_b = (const float*)d_in[15];
    const float* D1_w = (const float*)d_in[16];
    const float* D1_b = (const float*)d_in[17];
    const float* D2_w = (const float*)d_in[18];
    const float* D2_b = (const float*)d_in[19];

    float* ws  = (float*)d_ws;
    float* out = (float*)d_out;

    precomp_kernel<<<5, 128, 0, stream>>>(W_z, b_z, W_h, b_h,
                                          Lz_w, Lz_b, Lh_w, Lh_b, ws);
    tgcn_kernel<<<B_ * L_, 512, 0, stream>>>(x, ws, ws + WS_PART);
    pooldec_kernel<<<B_, 1024, 0, stream>>>(ws + WS_PART, D1_w, D1_b,
                                            D2_w, D2_b, out);
}

// Round 15
// 74.539 us; speedup vs baseline: 1.7627x; 1.1914x over previous
//
#include <hip/hip_runtime.h>
#include <hip/hip_bf16.h>
#include <math.h>

// Problem constants (match reference)
#define B_ 16
#define L_ 256
#define A_ 128
#define D_ 4
#define H_ 64
#define DFF_ 256
#define PRED_ 64
#define COUT_ 8

// ws layout (floats)
// gate weights SoA, exp2-prescaled: [g][d][64], g=0:z (x L2E), g=1:h (x 2*L2E)
#define WS_GW   0
// gate biases, same prescale: [g][64]
#define WS_GB   512
#define WS_PART 640                       // [B*L][64] per-(b,l) agent-sums

#define L2E 1.4426950408889634f

typedef float v2 __attribute__((ext_vector_type(2)));

// ---------------------------------------------------------------------------
// Kernel 0: fold gate weights, PARALLEL: 5 blocks x 128 threads, one output
// per thread. Wg' = (W_g @ Lg_w[0:64,:]) * s_g stored SoA [d][j]; bg'
// likewise. s_z = log2(e), s_h = 2*log2(e). R gate is dead code: dropped.
// ---------------------------------------------------------------------------
__global__ __launch_bounds__(128) void precomp_kernel(
    const float* __restrict__ W_z, const float* __restrict__ b_z,
    const float* __restrict__ W_h, const float* __restrict__ b_h,
    const float* __restrict__ Lz_w, const float* __restrict__ Lz_b,
    const float* __restrict__ Lh_w, const float* __restrict__ Lh_b,
    float* __restrict__ ws)
{
    const int idx = blockIdx.x * 128 + threadIdx.x;   // 0..639
    if (idx < 512) {
        const int g = idx >> 8;
        const int d = (idx >> 6) & 3;
        const int j = idx & 63;
        const float* W  = g ? W_h  : W_z;
        const float* Lw = g ? Lh_w : Lz_w;
        float acc = 0.f;
        #pragma unroll 8
        for (int h = 0; h < 64; ++h)
            acc += W[d * 64 + h] * Lw[h * 64 + j];
        ws[WS_GW + g * 256 + d * 64 + j] = acc * (g ? 2.f * L2E : L2E);
    } else {
        const int i = idx - 512;           // 0..127
        const int g = i >> 6;
        const int j = i & 63;
        const float* bg = g ? b_h  : b_z;
        const float* Lw = g ? Lh_w : Lz_w;
        const float* Lb = g ? Lh_b : Lz_b;
        float acc = Lb[j];
        #pragma unroll 8
        for (int h = 0; h < 64; ++h)
            acc += bg[h] * Lw[h * 64 + j];
        ws[WS_GB + g * 64 + j] = acc * (g ? 2.f * L2E : L2E);
    }
}

// ---------------------------------------------------------------------------
// Kernel 1: one block of 512 threads per (b,l). Each thread serves TWO agent
// rows (r, r+64) and one column-EIGHTH q (cols e = 8k|q, k=0..15). The 32
// pairwise weights (16 per row) are CACHED in fully-unrolled local arrays
// (registers) between pass 1 and pass 2 — combining r14's halved DS count
// (48 ds_read_b128/thread) with r8's cached-VALU count. FMA chains are
// v2-packed (VOP3P). Live set ~58-62 regs under (512,4)'s empirical cap 64
// (allocator law: cap ~ 256/arg2; r8:(512,6)->40, r14:(512,4)->52 measured).
//   w(r,e)  = min(rsq(|xr[r]-xr[e]|^2), 1e6)  (diag exact: rsq(0)=inf)
//   dinv[r] = rsq(sum_e w(r,e))
//   m[r]    = dinv[r] * sum_e w(r,e)*dinv[e]*xr[e]
//   h[r][j] = relu((1-sigmoid(zp))*tanh(hp)); part[bl][j] = sum_r h[r][j]
// ---------------------------------------------------------------------------
__global__ __launch_bounds__(512, 4) void tgcn_kernel(
    const float* __restrict__ x,
    const float* __restrict__ ws_w,
    float* __restrict__ part)
{
    __shared__ float4 xr4_s[128];     // agent features
    __shared__ float4 xs4_s[128];     // dinv[e]*xr[e]
    __shared__ float4 M4_s[128];      // per-row m (pre-scaled by dinv[r])
    __shared__ float  gw_s[512];      // [g][d][64] prescaled gate weights
    __shared__ float  gb_s[128];      // [g][64] prescaled gate biases
    __shared__ float  red_s[8][64];

    const int t  = threadIdx.x;
    const int bl = blockIdx.x;

    // ---- stage ----
    if (t < 128)
        xr4_s[t] = ((const float4*)(x + (size_t)bl * (A_ * D_)))[t];
    gw_s[t] = ws_w[WS_GW + t];
    if (t < 128) gb_s[t] = ws_w[WS_GB + t];
    __syncthreads();

    const int r = t >> 3;             // row pair: rows r, r+64  (r in 0..63)
    const int q = t & 7;              // column-eighth (interleaved)

    const float4 xa0 = xr4_s[r];
    const float4 xa1 = xr4_s[r + 64];
    const v2 a0_01 = {xa0.x, xa0.y};
    const v2 a0_23 = {xa0.z, xa0.w};
    const v2 a1_01 = {xa1.x, xa1.y};
    const v2 a1_23 = {xa1.z, xa1.w};

    // ---- pass 1: pairwise weights for both rows -> reg cache + rowsums ----
    float wu[16];                     // weights for row r      (16 regs)
    float wv[16];                     // weights for row r+64   (16 regs)
    float rsA = 0.f, rsB = 0.f;
    #pragma unroll
    for (int k = 0; k < 16; ++k) {
        float4 xe = xr4_s[(k << 3) | q];       // one read, two rows
        v2 e01 = {xe.x, xe.y};
        v2 e23 = {xe.z, xe.w};
        v2 dA01 = a0_01 - e01;
        v2 dA23 = a0_23 - e23;
        v2 sA = dA01 * dA01;
        sA = __builtin_elementwise_fma(dA23, dA23, sA);
        float wA = fminf(__builtin_amdgcn_rsqf(sA.x + sA.y), 1.0e6f);
        v2 dB01 = a1_01 - e01;
        v2 dB23 = a1_23 - e23;
        v2 sB = dB01 * dB01;
        sB = __builtin_elementwise_fma(dB23, dB23, sB);
        float wB = fminf(__builtin_amdgcn_rsqf(sB.x + sB.y), 1.0e6f);
        wu[k] = wA;
        wv[k] = wB;
        rsA += wA;
        rsB += wB;
    }
    rsA += __shfl_xor(rsA, 1); rsA += __shfl_xor(rsA, 2); rsA += __shfl_xor(rsA, 4);
    rsB += __shfl_xor(rsB, 1); rsB += __shfl_xor(rsB, 2); rsB += __shfl_xor(rsB, 4);
    const float dinvA = __builtin_amdgcn_rsqf(rsA);
    const float dinvB = __builtin_amdgcn_rsqf(rsB);
    if (q == 0) {
        xs4_s[r]      = make_float4(dinvA * xa0.x, dinvA * xa0.y,
                                    dinvA * xa0.z, dinvA * xa0.w);
        xs4_s[r + 64] = make_float4(dinvB * xa1.x, dinvB * xa1.y,
                                    dinvB * xa1.z, dinvB * xa1.w);
    }
    __syncthreads();

    // ---- pass 2: m(row) = w_row . xs using cached weights ----
    v2 mA01 = {0.f, 0.f};
    v2 mA23 = {0.f, 0.f};
    v2 mB01 = {0.f, 0.f};
    v2 mB23 = {0.f, 0.f};
    #pragma unroll
    for (int k = 0; k < 16; ++k) {
        float4 xu = xs4_s[(k << 3) | q];       // one read, two rows
        v2 u01 = {xu.x, xu.y};
        v2 u23 = {xu.z, xu.w};
        v2 wA2 = {wu[k], wu[k]};
        v2 wB2 = {wv[k], wv[k]};
        mA01 = __builtin_elementwise_fma(wA2, u01, mA01);
        mA23 = __builtin_elementwise_fma(wA2, u23, mA23);
        mB01 = __builtin_elementwise_fma(wB2, u01, mB01);
        mB23 = __builtin_elementwise_fma(wB2, u23, mB23);
    }
    float mA0 = mA01.x, mA1 = mA01.y, mA2 = mA23.x, mA3 = mA23.y;
    float mB0 = mB01.x, mB1 = mB01.y, mB2 = mB23.x, mB3 = mB23.y;
    mA0 += __shfl_xor(mA0, 1); mA0 += __shfl_xor(mA0, 2); mA0 += __shfl_xor(mA0, 4);
    mA1 += __shfl_xor(mA1, 1); mA1 += __shfl_xor(mA1, 2); mA1 += __shfl_xor(mA1, 4);
    mA2 += __shfl_xor(mA2, 1); mA2 += __shfl_xor(mA2, 2); mA2 += __shfl_xor(mA2, 4);
    mA3 += __shfl_xor(mA3, 1); mA3 += __shfl_xor(mA3, 2); mA3 += __shfl_xor(mA3, 4);
    mB0 += __shfl_xor(mB0, 1); mB0 += __shfl_xor(mB0, 2); mB0 += __shfl_xor(mB0, 4);
    mB1 += __shfl_xor(mB1, 1); mB1 += __shfl_xor(mB1, 2); mB1 += __shfl_xor(mB1, 4);
    mB2 += __shfl_xor(mB2, 1); mB2 += __shfl_xor(mB2, 2); mB2 += __shfl_xor(mB2, 4);
    mB3 += __shfl_xor(mB3, 1); mB3 += __shfl_xor(mB3, 2); mB3 += __shfl_xor(mB3, 4);
    if (q == 0) {
        M4_s[r]      = make_float4(dinvA * mA0, dinvA * mA1,
                                   dinvA * mA2, dinvA * mA3);
        M4_s[r + 64] = make_float4(dinvB * mB0, dinvB * mB1,
                                   dinvB * mB2, dinvB * mB3);
    }
    __syncthreads();

    // ---- gates, transposed: thread <-> column j, 16 agents per wave ----
    {
        const int j = t & 63;
        const int g = t >> 6;                  // wave id 0..7 -> agent group
        const v2 W0 = {gw_s[j],       gw_s[256 + j]};
        const v2 W1 = {gw_s[64 + j],  gw_s[320 + j]};
        const v2 W2 = {gw_s[128 + j], gw_s[384 + j]};
        const v2 W3 = {gw_s[192 + j], gw_s[448 + j]};
        const v2 Bzh = {gb_s[j], gb_s[64 + j]};
        float acc = 0.f;
        #pragma unroll
        for (int i = 0; i < 16; ++i) {
            float4 mv = M4_s[g * 16 + i];      // wave-uniform broadcast
            v2 zh = __builtin_elementwise_fma((v2){mv.x, mv.x}, W0, Bzh);
            zh = __builtin_elementwise_fma((v2){mv.y, mv.y}, W1, zh);
            zh = __builtin_elementwise_fma((v2){mv.z, mv.z}, W2, zh);
            zh = __builtin_elementwise_fma((v2){mv.w, mv.w}, W3, zh);
            float ez = __builtin_amdgcn_exp2f(zh.x);
            float e2 = __builtin_amdgcn_exp2f(zh.y);
            // (1-sigmoid)*tanh = (e2-1) / ((1+ez)*(1+e2)), one rcp
            float num = e2 - 1.f;
            float den = (1.f + ez) * (1.f + e2);
            float hv  = num * __builtin_amdgcn_rcpf(den);
            acc += fmaxf(hv, 0.f);
        }
        red_s[g][j] = acc;
    }
    __syncthreads();

    if (t < 64) {
        float s = red_s[0][t] + red_s[1][t] + red_s[2][t] + red_s[3][t]
                + red_s[4][t] + red_s[5][t] + red_s[6][t] + red_s[7][t];
        part[(size_t)bl * 64 + t] = s;
    }
}

// ---------------------------------------------------------------------------
// Kernel 2: fused pool + decoder. One block of 1024 threads per batch.
// ---------------------------------------------------------------------------
__global__ __launch_bounds__(1024) void pooldec_kernel(
    const float* __restrict__ part,
    const float* __restrict__ D1_w, const float* __restrict__ D1_b,
    const float* __restrict__ D2_w, const float* __restrict__ D2_b,
    float* __restrict__ out)
{
    __shared__ float red_s[16][64];
    __shared__ float pooled_s[64];
    __shared__ float t1_s[256];
    const int t = threadIdx.x, b = blockIdx.x;

    // ---- pool over L: 16 groups x 16 rows ----
    {
        const int j = t & 63, g = t >> 6;
        const float* pb = part + ((size_t)b * L_ + g * 16) * 64;
        float s = 0.f;
        #pragma unroll
        for (int i = 0; i < 16; ++i) s += pb[i * 64 + j];
        red_s[g][j] = s;
    }
    __syncthreads();
    if (t < 64) {
        float s = 0.f;
        #pragma unroll
        for (int g = 0; g < 16; ++g) s += red_s[g][t];
        pooled_s[t] = s * (1.f / ((float)L_ * (float)A_));
    }
    __syncthreads();

    // ---- D1: 256 outputs, 4 threads per output (16 h each) ----
    {
        const int o = t >> 2, sub = t & 3;
        float acc = 0.f;
        #pragma unroll
        for (int hh = 0; hh < 16; ++hh) {
            int h = sub * 16 + hh;
            acc += pooled_s[h] * D1_w[h * 256 + o];
        }
        acc += __shfl_xor(acc, 1);
        acc += __shfl_xor(acc, 2);
        if (sub == 0) t1_s[o] = fmaxf(acc + D1_b[o], 0.f);
    }
    __syncthreads();

    // ---- D2: 512 outputs, 2 threads per output (128 k each) ----
    {
        const int o = t >> 1, kh = t & 1;
        float acc = 0.f;
        for (int kk = 0; kk < 128; ++kk) {
            int k = kh * 128 + kk;
            acc += t1_s[k] * D2_w[k * 512 + o];
        }
        acc += __shfl_xor(acc, 1);
        if (kh == 0) out[(size_t)b * 512 + o] = acc + D2_b[o];
    }
}

// ---------------------------------------------------------------------------
extern "C" void kernel_launch(void* const* d_in, const int* in_sizes, int n_in,
                              void* d_out, int out_size, void* d_ws, size_t ws_size,
                              hipStream_t stream)
{
    const float* x    = (const float*)d_in[0];
    // d_in[1..3]: x_mark_enc, x_dec, x_mark_dec — unused by the reference
    const float* W_z  = (const float*)d_in[4];
    const float* b_z  = (const float*)d_in[5];
    // d_in[6], d_in[7]: W_r, b_r — dead code in the reference
    const float* W_h  = (const float*)d_in[8];
    const float* b_h  = (const float*)d_in[9];
    const float* Lz_w = (const float*)d_in[10];
    const float* Lz_b = (const float*)d_in[11];
    // d_in[12], d_in[13]: Lr_w, Lr_b — dead
    const float* Lh_w = (const float*)d_in[14];
    const float* Lh_b = (const float*)d_in[15];
    const float* D1_w = (const float*)d_in[16];
    const float* D1_b = (const float*)d_in[17];
    const float* D2_w = (const float*)d_in[18];
    const float* D2_b = (const float*)d_in[19];

    float* ws  = (float*)d_ws;
    float* out = (float*)d_out;

    precomp_kernel<<<5, 128, 0, stream>>>(W_z, b_z, W_h, b_h,
                                          Lz_w, Lz_b, Lh_w, Lh_b, ws);
    tgcn_kernel<<<B_ * L_, 512, 0, stream>>>(x, ws, ws + WS_PART);
    pooldec_kernel<<<B_, 1024, 0, stream>>>(ws + WS_PART, D1_w, D1_b,
                                            D2_w, D2_b, out);
}

// Round 16
// 69.702 us; speedup vs baseline: 1.8850x; 1.0694x over previous
//
#include <hip/hip_runtime.h>
#include <hip/hip_bf16.h>
#include <math.h>

// Problem constants (match reference)
#define B_ 16
#define L_ 256
#define A_ 128
#define D_ 4
#define H_ 64
#define DFF_ 256
#define PRED_ 64
#define COUT_ 8

// ws layout (floats)
// gate weights SoA, exp2-prescaled: [g][d][64], g=0:z (x L2E), g=1:h (x 2*L2E)
#define WS_GW   0
// gate biases, same prescale: [g][64]
#define WS_GB   512
#define WS_PART 640                       // [B*L][64] per-(b,l) agent-sums

#define L2E 1.4426950408889634f

typedef float v2 __attribute__((ext_vector_type(2)));

// ---------------------------------------------------------------------------
// Kernel 0: fold gate weights, PARALLEL: 5 blocks x 128 threads, one output
// per thread. Wg' = (W_g @ Lg_w[0:64,:]) * s_g stored SoA [d][j]; bg'
// likewise. s_z = log2(e), s_h = 2*log2(e). R gate is dead code: dropped.
// ---------------------------------------------------------------------------
__global__ __launch_bounds__(128) void precomp_kernel(
    const float* __restrict__ W_z, const float* __restrict__ b_z,
    const float* __restrict__ W_h, const float* __restrict__ b_h,
    const float* __restrict__ Lz_w, const float* __restrict__ Lz_b,
    const float* __restrict__ Lh_w, const float* __restrict__ Lh_b,
    float* __restrict__ ws)
{
    const int idx = blockIdx.x * 128 + threadIdx.x;   // 0..639
    if (idx < 512) {
        const int g = idx >> 8;
        const int d = (idx >> 6) & 3;
        const int j = idx & 63;
        const float* W  = g ? W_h  : W_z;
        const float* Lw = g ? Lh_w : Lz_w;
        float acc = 0.f;
        #pragma unroll 8
        for (int h = 0; h < 64; ++h)
            acc += W[d * 64 + h] * Lw[h * 64 + j];
        ws[WS_GW + g * 256 + d * 64 + j] = acc * (g ? 2.f * L2E : L2E);
    } else {
        const int i = idx - 512;           // 0..127
        const int g = i >> 6;
        const int j = i & 63;
        const float* bg = g ? b_h  : b_z;
        const float* Lw = g ? Lh_w : Lz_w;
        const float* Lb = g ? Lh_b : Lz_b;
        float acc = Lb[j];
        #pragma unroll 8
        for (int h = 0; h < 64; ++h)
            acc += bg[h] * Lw[h * 64 + j];
        ws[WS_GB + g * 64 + j] = acc * (g ? 2.f * L2E : L2E);
    }
}

// ---------------------------------------------------------------------------
// Kernel 1 (round-9 configuration, the measured optimum of this family):
// one block of 512 threads per (b,l); 4 threads per agent-row, interleaved
// columns e = 4k+q (conflict-free LDS reads). The 32 pairwise weights are
// computed once (pass 1), cached in 32 NAMED registers (macro SSA), reused
// in pass 2. v2-packed FMA chains (VOP3P). (512,6) -> VGPR 40, no spill,
// ~53% occupancy; sits on the DS-issue roofline (80 ds_read_b128 x 12 cyc
// x 128 waves/CU = 123K cyc = 51 us), VALU ~70% overlapped.
// Measured session-wide alternatives: 2-row/256thr = 51 (occupancy stall),
// 2-row recompute = 75 (VALU-bound), 2-row 8thr/row = 58 (dep-bound),
// 64-reg cache = spill. This is the saddle point.
// ---------------------------------------------------------------------------
#define REP32(M) M(0) M(1) M(2) M(3) M(4) M(5) M(6) M(7) \
                 M(8) M(9) M(10) M(11) M(12) M(13) M(14) M(15) \
                 M(16) M(17) M(18) M(19) M(20) M(21) M(22) M(23) \
                 M(24) M(25) M(26) M(27) M(28) M(29) M(30) M(31)

__global__ __launch_bounds__(512, 6) void tgcn_kernel(
    const float* __restrict__ x,
    const float* __restrict__ ws_w,
    float* __restrict__ part)
{
    __shared__ float4 xr4_s[128];     // agent features
    __shared__ float4 xs4_s[128];     // dinv[e]*xr[e]
    __shared__ float4 M4_s[128];      // per-row m (pre-scaled by dinv[r])
    __shared__ float  gw_s[512];      // [g][d][64] prescaled gate weights
    __shared__ float  gb_s[128];      // [g][64] prescaled gate biases
    __shared__ float  red_s[8][64];

    const int t  = threadIdx.x;
    const int bl = blockIdx.x;

    // ---- stage ----
    if (t < 128) {
        xr4_s[t] = ((const float4*)(x + (size_t)bl * (A_ * D_)))[t];
    } else if (t < 384) {
        int i = t - 128;
        gw_s[i]       = ws_w[WS_GW + i];
        gw_s[i + 256] = ws_w[WS_GW + i + 256];
    } else {
        gb_s[t - 384] = ws_w[WS_GB + (t - 384)];
    }
    __syncthreads();

    const int r = t >> 2;           // agent row 0..127
    const int q = t & 3;            // column-quarter (interleaved)

    const float4 xa = xr4_s[r];
    const v2 xa01 = {xa.x, xa.y};
    const v2 xa23 = {xa.z, xa.w};

    // ---- pass 1: pairwise weights -> named regs + rowsum ----
#define DECLW(i) float w##i;
    REP32(DECLW)
#undef DECLW
    float rs0 = 0.f, rs1 = 0.f;
#define PASS1(i) { \
        float4 xe = xr4_s[((i) << 2) | q]; \
        v2 d01 = xa01 - (v2){xe.x, xe.y}; \
        v2 d23 = xa23 - (v2){xe.z, xe.w}; \
        v2 s2 = d01 * d01; \
        s2 = __builtin_elementwise_fma(d23, d23, s2); \
        float d2 = s2.x + s2.y; \
        w##i = fminf(__builtin_amdgcn_rsqf(d2), 1.0e6f); \
        if ((i) & 1) rs1 += w##i; else rs0 += w##i; }
    REP32(PASS1)
#undef PASS1
    float rs = rs0 + rs1;
    rs += __shfl_xor(rs, 1);
    rs += __shfl_xor(rs, 2);                   // all 4 lanes have full rowsum
    const float dinv = __builtin_amdgcn_rsqf(rs);
    if (q == 0)
        xs4_s[r] = make_float4(dinv * xa.x, dinv * xa.y, dinv * xa.z, dinv * xa.w);
    __syncthreads();

    // ---- pass 2: m = w_row . xs using cached weights (2 pk_fma/pair) ----
    v2 mA = {0.f, 0.f};
    v2 mB = {0.f, 0.f};
#define PASS2(i) { \
        float4 u = xs4_s[((i) << 2) | q]; \
        v2 wv2 = {w##i, w##i}; \
        mA = __builtin_elementwise_fma(wv2, (v2){u.x, u.y}, mA); \
        mB = __builtin_elementwise_fma(wv2, (v2){u.z, u.w}, mB); }
    REP32(PASS2)
#undef PASS2
    float m0 = mA.x, m1 = mA.y, m2 = mB.x, m3 = mB.y;
    m0 += __shfl_xor(m0, 1); m0 += __shfl_xor(m0, 2);
    m1 += __shfl_xor(m1, 1); m1 += __shfl_xor(m1, 2);
    m2 += __shfl_xor(m2, 1); m2 += __shfl_xor(m2, 2);
    m3 += __shfl_xor(m3, 1); m3 += __shfl_xor(m3, 2);
    if (q == 0)
        M4_s[r] = make_float4(dinv * m0, dinv * m1, dinv * m2, dinv * m3);
    __syncthreads();

    // ---- gates, transposed: thread <-> column j, 16 agents per wave ----
    {
        const int j  = t & 63;
        const int g  = t >> 6;                 // wave id 0..7 -> agent group
        const v2 W0 = {gw_s[j],       gw_s[256 + j]};
        const v2 W1 = {gw_s[64 + j],  gw_s[320 + j]};
        const v2 W2 = {gw_s[128 + j], gw_s[384 + j]};
        const v2 W3 = {gw_s[192 + j], gw_s[448 + j]};
        const v2 Bzh = {gb_s[j], gb_s[64 + j]};
        float acc = 0.f;
        #pragma unroll
        for (int i = 0; i < 16; ++i) {
            float4 mv = M4_s[g * 16 + i];      // wave-uniform broadcast
            v2 zh = __builtin_elementwise_fma((v2){mv.x, mv.x}, W0, Bzh);
            zh = __builtin_elementwise_fma((v2){mv.y, mv.y}, W1, zh);
            zh = __builtin_elementwise_fma((v2){mv.z, mv.z}, W2, zh);
            zh = __builtin_elementwise_fma((v2){mv.w, mv.w}, W3, zh);
            float ez = __builtin_amdgcn_exp2f(zh.x);
            float e2 = __builtin_amdgcn_exp2f(zh.y);
            // (1-sigmoid)*tanh = (e2-1) / ((1+ez)*(1+e2)), one rcp
            float num = e2 - 1.f;
            float den = (1.f + ez) * (1.f + e2);
            float hv  = num * __builtin_amdgcn_rcpf(den);
            acc += fmaxf(hv, 0.f);
        }
        red_s[g][j] = acc;
    }
    __syncthreads();

    if (t < 64) {
        float s = red_s[0][t] + red_s[1][t] + red_s[2][t] + red_s[3][t]
                + red_s[4][t] + red_s[5][t] + red_s[6][t] + red_s[7][t];
        part[(size_t)bl * 64 + t] = s;
    }
}

// ---------------------------------------------------------------------------
// Kernel 2: fused pool + decoder. One block of 1024 threads per batch.
// ---------------------------------------------------------------------------
__global__ __launch_bounds__(1024) void pooldec_kernel(
    const float* __restrict__ part,
    const float* __restrict__ D1_w, const float* __restrict__ D1_b,
    const float* __restrict__ D2_w, const float* __restrict__ D2_b,
    float* __restrict__ out)
{
    __shared__ float red_s[16][64];
    __shared__ float pooled_s[64];
    __shared__ float t1_s[256];
    const int t = threadIdx.x, b = blockIdx.x;

    // ---- pool over L: 16 groups x 16 rows ----
    {
        const int j = t & 63, g = t >> 6;
        const float* pb = part + ((size_t)b * L_ + g * 16) * 64;
        float s = 0.f;
        #pragma unroll
        for (int i = 0; i < 16; ++i) s += pb[i * 64 + j];
        red_s[g][j] = s;
    }
    __syncthreads();
    if (t < 64) {
        float s = 0.f;
        #pragma unroll
        for (int g = 0; g < 16; ++g) s += red_s[g][t];
        pooled_s[t] = s * (1.f / ((float)L_ * (float)A_));
    }
    __syncthreads();

    // ---- D1: 256 outputs, 4 threads per output (16 h each) ----
    {
        const int o = t >> 2, sub = t & 3;
        float acc = 0.f;
        #pragma unroll
        for (int hh = 0; hh < 16; ++hh) {
            int h = sub * 16 + hh;
            acc += pooled_s[h] * D1_w[h * 256 + o];
        }
        acc += __shfl_xor(acc, 1);
        acc += __shfl_xor(acc, 2);
        if (sub == 0) t1_s[o] = fmaxf(acc + D1_b[o], 0.f);
    }
    __syncthreads();

    // ---- D2: 512 outputs, 2 threads per output (128 k each) ----
    {
        const int o = t >> 1, kh = t & 1;
        float acc = 0.f;
        for (int kk = 0; kk < 128; ++kk) {
            int k = kh * 128 + kk;
            acc += t1_s[k] * D2_w[k * 512 + o];
        }
        acc += __shfl_xor(acc, 1);
        if (kh == 0) out[(size_t)b * 512 + o] = acc + D2_b[o];
    }
}

// ---------------------------------------------------------------------------
extern "C" void kernel_launch(void* const* d_in, const int* in_sizes, int n_in,
                              void* d_out, int out_size, void* d_ws, size_t ws_size,
                              hipStream_t stream)
{
    const float* x    = (const float*)d_in[0];
    // d_in[1..3]: x_mark_enc, x_dec, x_mark_dec — unused by the reference
    const float* W_z  = (const float*)d_in[4];
    const float* b_z  = (const float*)d_in[5];
    // d_in[6], d_in[7]: W_r, b_r — dead code in the reference
    const float* W_h  = (const float*)d_in[8];
    const float* b_h  = (const float*)d_in[9];
    const float* Lz_w = (const float*)d_in[10];
    const float* Lz_b = (const float*)d_in[11];
    // d_in[12], d_in[13]: Lr_w, Lr_b — dead
    const float* Lh_w = (const float*)d_in[14];
    const float* Lh_b = (const float*)d_in[15];
    const float* D1_w = (const float*)d_in[16];
    const float* D1_b = (const float*)d_in[17];
    const float* D2_w = (const float*)d_in[18];
    const float* D2_b = (const float*)d_in[19];

    float* ws  = (float*)d_ws;
    float* out = (float*)d_out;

    precomp_kernel<<<5, 128, 0, stream>>>(W_z, b_z, W_h, b_h,
                                          Lz_w, Lz_b, Lh_w, Lh_b, ws);
    tgcn_kernel<<<B_ * L_, 512, 0, stream>>>(x, ws, ws + WS_PART);
    pooldec_kernel<<<B_, 1024, 0, stream>>>(ws + WS_PART, D1_w, D1_b,
                                            D2_w, D2_b, out);
}